// Round 2
// baseline (16531.317 us; speedup 1.0000x reference)
//
#include <hip/hip_runtime.h>

typedef unsigned short u16;
typedef unsigned int u32;

#define NB 32
#define TE 512
#define LD 128
#define EDIM 256
#define H1 1024
#define KD 128
#define G1N 4096
#define K1N 1408
#define G2N 512

__device__ __forceinline__ float bfl(u32 u){ return __uint_as_float(u << 16); }
__device__ __forceinline__ float bfh(u32 u){ return __uint_as_float(u & 0xffff0000u); }
__device__ __forceinline__ float bf1(u16 v){ return __uint_as_float(((u32)v) << 16); }
__device__ __forceinline__ u16 f2bf(float f){
  u32 x = __float_as_uint(f);
  return (u16)((x + 0x7fffu + ((x >> 16) & 1u)) >> 16);
}
__device__ __forceinline__ float sigf(float x){ return 1.0f / (1.0f + __expf(-x)); }

// ---- init: zero h1,c1a,c1b,h2,c2 (106496 floats) then ctx = values[:,0,:] (4096)
__global__ void k_init(float* __restrict__ zbase, const float* __restrict__ values){
  int idx = blockIdx.x * 256 + threadIdx.x;   // grid 432*256 = 110592 exactly
  if (idx < 106496) { zbase[idx] = 0.0f; }
  else {
    int j = idx - 106496;          // 0..4095
    int n = j >> 7, v = j & 127;
    zbase[idx] = values[(size_t)n * TE * KD + v];
  }
}

// ---- LSTM1 gate partial dots. grid (256 ug, 2 ks), block 256.
// inp = [x(256) | ctx(128) | h1(1024)], staged bf16 in LDS; weights fp32 direct.
__global__ __launch_bounds__(256) void k_gates1(
    int t, const int* __restrict__ text, const float* __restrict__ emb,
    const float* __restrict__ Wih1, const float* __restrict__ Whh1,
    const float* __restrict__ ctxg, const float* __restrict__ h1g,
    float* __restrict__ gp1)
{
  __shared__ __align__(16) u16 s_inp[32 * 712];
  __shared__ int s_tok[32];
  int tid = threadIdx.x;
  int ug = blockIdx.x;      // unit group: units 4*ug..4*ug+3
  int ks = blockIdx.y;      // k half
  if (tid < 32) s_tok[tid] = (t == 0) ? 1 : text[tid * LD + (t - 1)];
  __syncthreads();
  int k0 = ks * 704;
  for (int i = tid; i < 32 * 704; i += 256){
    int r = i / 704, c = i - r * 704;
    int gk = k0 + c;
    float fv;
    if (gk < 256)       fv = emb[(size_t)s_tok[r] * EDIM + gk];
    else if (gk < 384)  fv = ctxg[r * KD + (gk - 256)];
    else                fv = h1g[r * H1 + (gk - 384)];
    s_inp[r * 712 + c] = f2bf(fv);
  }
  __syncthreads();
  int n = tid & 31, slot = tid >> 5;
  int us = slot >> 1, gp = slot & 1;
  int u = ug * 4 + us;
  int ja = (2 * gp) * H1 + u;   // gate 0 (i) or 2 (g)
  int jb = ja + H1;             // gate 1 (f) or 3 (o)
  // weight segments: ks=0 -> Wih1[384] + Whh1[0:320); ks=1 -> Whh1[320:1024)
  const float4 *wa0, *wb0, *wa1, *wb1;
  int q0, q1;
  if (ks == 0){
    wa0 = (const float4*)(Wih1 + (size_t)ja * 384);
    wb0 = (const float4*)(Wih1 + (size_t)jb * 384);
    wa1 = (const float4*)(Whh1 + (size_t)ja * H1);
    wb1 = (const float4*)(Whh1 + (size_t)jb * H1);
    q0 = 48; q1 = 40;
  } else {
    wa0 = (const float4*)(Whh1 + (size_t)ja * H1 + 320);
    wb0 = (const float4*)(Whh1 + (size_t)jb * H1 + 320);
    wa1 = wa0; wb1 = wb0;
    q0 = 88; q1 = 0;
  }
  const uint4* xr = (const uint4*)(s_inp + n * 712);
  float aa = 0.0f, ab = 0.0f;
  int q = 0;
#define DOT8(WA, WB, QQ) { uint4 iv = xr[q]; \
    float i0 = bfl(iv.x), i1 = bfh(iv.x), i2 = bfl(iv.y), i3 = bfh(iv.y); \
    float i4 = bfl(iv.z), i5 = bfh(iv.z), i6 = bfl(iv.w), i7 = bfh(iv.w); \
    float4 a0 = WA[2*(QQ)], a1 = WA[2*(QQ)+1]; \
    float4 b0 = WB[2*(QQ)], b1 = WB[2*(QQ)+1]; \
    aa += i0*a0.x + i1*a0.y + i2*a0.z + i3*a0.w; \
    aa += i4*a1.x + i5*a1.y + i6*a1.z + i7*a1.w; \
    ab += i0*b0.x + i1*b0.y + i2*b0.z + i3*b0.w; \
    ab += i4*b1.x + i5*b1.y + i6*b1.z + i7*b1.w; }
  #pragma unroll 4
  for (int qq = 0; qq < q0; qq++, q++) DOT8(wa0, wb0, qq)
  #pragma unroll 4
  for (int qq = 0; qq < q1; qq++, q++) DOT8(wa1, wb1, qq)
#undef DOT8
  float* g = gp1 + (size_t)ks * (NB * G1N) + n * G1N;
  g[ja] = aa;
  g[jb] = ab;
}

// ---- cell1 (from gp1) + LSTM2 gate partial dots -> gp2. grid (4 p, 16 jg), block 256.
__global__ __launch_bounds__(256) void k_cell1_gates2(
    const float* __restrict__ gp1, const float* __restrict__ bih1, const float* __restrict__ bhh1,
    const float* __restrict__ c1in, float* __restrict__ c1out,
    float* __restrict__ h1g, const float* __restrict__ h2g,
    const float* __restrict__ Wih2, const float* __restrict__ Whh2,
    float* __restrict__ gp2)
{
  __shared__ __align__(16) u16 s2[32 * 296];
  int tid = threadIdx.x;
  int p = blockIdx.x;     // k part: cols [288p, 288p+288) of [h1(1024)|h2(128)]
  int jg = blockIdx.y;    // 0..15, output units 8*jg..8*jg+7 (x4 gates)
  int u0 = p * 288;
  int ucnt = (p == 3) ? 160 : 288;
  // cell1 for h1 units in this k-range (redundant across jg; jg==0 writes state)
  for (int i = tid; i < 32 * ucnt; i += 256){
    int n = i / ucnt, cc = i - n * ucnt;
    int uu = u0 + cc;
    const float* g0 = gp1 + (size_t)n * G1N;
    const float* g1 = gp1 + (size_t)(NB * G1N) + (size_t)n * G1N;
    float gi = g0[uu]        + g1[uu]        + bih1[uu]        + bhh1[uu];
    float gf = g0[H1+uu]     + g1[H1+uu]     + bih1[H1+uu]     + bhh1[H1+uu];
    float gg = g0[2*H1+uu]   + g1[2*H1+uu]   + bih1[2*H1+uu]   + bhh1[2*H1+uu];
    float go = g0[3*H1+uu]   + g1[3*H1+uu]   + bih1[3*H1+uu]   + bhh1[3*H1+uu];
    gi = sigf(gi); gf = sigf(gf); gg = tanhf(gg); go = sigf(go);
    float cold = c1in[n * H1 + uu];
    float cn = gf * cold + gi * gg;
    float hn = go * tanhf(cn);
    s2[n * 296 + cc] = f2bf(hn);
    if (jg == 0){ c1out[n * H1 + uu] = cn; h1g[n * H1 + uu] = hn; }
  }
  if (p == 3){
    for (int i = tid; i < 32 * 128; i += 256){
      int n = i >> 7, cc = i & 127;
      s2[n * 296 + 160 + cc] = f2bf(h2g[i]);
    }
  }
  __syncthreads();
  int n = tid & 31, u2s = tid >> 5;      // u2s 0..7
  int u2 = jg * 8 + u2s;                 // 0..127
  // weight segments: p<3 -> Wih2 row cols [u0,u0+288); p==3 -> Wih2[864:1024) + Whh2[0:128)
  const float4 *w0a, *w1a, *w2a, *w3a, *w0b, *w1b, *w2b, *w3b;
  int qA, qB;
  if (p < 3){
    w0a = (const float4*)(Wih2 + (size_t)(0*KD + u2) * H1 + u0);
    w1a = (const float4*)(Wih2 + (size_t)(1*KD + u2) * H1 + u0);
    w2a = (const float4*)(Wih2 + (size_t)(2*KD + u2) * H1 + u0);
    w3a = (const float4*)(Wih2 + (size_t)(3*KD + u2) * H1 + u0);
    w0b = w0a; w1b = w1a; w2b = w2a; w3b = w3a;
    qA = 36; qB = 0;
  } else {
    w0a = (const float4*)(Wih2 + (size_t)(0*KD + u2) * H1 + 864);
    w1a = (const float4*)(Wih2 + (size_t)(1*KD + u2) * H1 + 864);
    w2a = (const float4*)(Wih2 + (size_t)(2*KD + u2) * H1 + 864);
    w3a = (const float4*)(Wih2 + (size_t)(3*KD + u2) * H1 + 864);
    w0b = (const float4*)(Whh2 + (size_t)(0*KD + u2) * KD);
    w1b = (const float4*)(Whh2 + (size_t)(1*KD + u2) * KD);
    w2b = (const float4*)(Whh2 + (size_t)(2*KD + u2) * KD);
    w3b = (const float4*)(Whh2 + (size_t)(3*KD + u2) * KD);
    qA = 20; qB = 16;
  }
  const uint4* xr = (const uint4*)(s2 + n * 296);
  float a0 = 0.f, a1 = 0.f, a2 = 0.f, a3 = 0.f;
  int q = 0;
#define DOT8x4(W0, W1, W2, W3, QQ) { uint4 iv = xr[q]; \
    float i0 = bfl(iv.x), i1 = bfh(iv.x), i2 = bfl(iv.y), i3 = bfh(iv.y); \
    float i4 = bfl(iv.z), i5 = bfh(iv.z), i6 = bfl(iv.w), i7 = bfh(iv.w); \
    float4 c0 = W0[2*(QQ)], c1 = W0[2*(QQ)+1]; \
    a0 += i0*c0.x + i1*c0.y + i2*c0.z + i3*c0.w + i4*c1.x + i5*c1.y + i6*c1.z + i7*c1.w; \
    float4 d0 = W1[2*(QQ)], d1 = W1[2*(QQ)+1]; \
    a1 += i0*d0.x + i1*d0.y + i2*d0.z + i3*d0.w + i4*d1.x + i5*d1.y + i6*d1.z + i7*d1.w; \
    float4 e0 = W2[2*(QQ)], e1 = W2[2*(QQ)+1]; \
    a2 += i0*e0.x + i1*e0.y + i2*e0.z + i3*e0.w + i4*e1.x + i5*e1.y + i6*e1.z + i7*e1.w; \
    float4 f0 = W3[2*(QQ)], f1 = W3[2*(QQ)+1]; \
    a3 += i0*f0.x + i1*f0.y + i2*f0.z + i3*f0.w + i4*f1.x + i5*f1.y + i6*f1.z + i7*f1.w; }
  #pragma unroll 4
  for (int qq = 0; qq < qA; qq++, q++) DOT8x4(w0a, w1a, w2a, w3a, qq)
  #pragma unroll 4
  for (int qq = 0; qq < qB; qq++, q++) DOT8x4(w0b, w1b, w2b, w3b, qq)
#undef DOT8x4
  float* g = gp2 + ((size_t)p * NB + n) * G2N;
  g[u2] = a0; g[KD + u2] = a1; g[2*KD + u2] = a2; g[3*KD + u2] = a3;
}

// ---- reduce gp2 -> cell2 -> attention -> ctx; writes aall row t-1. grid 32, block 512.
__global__ __launch_bounds__(512) void k_attn(
    int t, const float* __restrict__ key, const float* __restrict__ values,
    const int* __restrict__ elen,
    const float* __restrict__ bih2, const float* __restrict__ bhh2,
    const float* __restrict__ gp2, float* __restrict__ h2g, float* __restrict__ c2g,
    float* __restrict__ ctxg, u16* __restrict__ aall)
{
  __shared__ float s_h2[128];
  __shared__ float s_e[512];
  __shared__ float s_part[4][128];
  __shared__ float s_red[8];
  __shared__ float s_scal[2];
  int tid = threadIdx.x;
  int n = blockIdx.x;
  if (tid < 128){
    int u = tid;
    float g[4];
    #pragma unroll
    for (int e = 0; e < 4; e++){
      int j = e * KD + u;
      float s = bih2[j] + bhh2[j];
      #pragma unroll
      for (int pp = 0; pp < 4; pp++) s += gp2[((size_t)pp * NB + n) * G2N + j];
      g[e] = s;
    }
    float gi = sigf(g[0]), gf = sigf(g[1]), gt = tanhf(g[2]), go = sigf(g[3]);
    float cn = gf * c2g[n * KD + u] + gi * gt;
    c2g[n * KD + u] = cn;
    float hn = go * tanhf(cn);
    h2g[n * KD + u] = hn;
    s_h2[u] = hn;
    aall[((size_t)(t - 1) * NB + n) * 256 + u] = f2bf(hn);
  }
  __syncthreads();
  int el = elen[n];
  const float4* krow = (const float4*)(key + ((size_t)n * TE + tid) * KD);
  float e = 0.0f;
  #pragma unroll 8
  for (int q = 0; q < 32; q++){
    float4 w = krow[q];
    e += w.x*s_h2[4*q+0] + w.y*s_h2[4*q+1] + w.z*s_h2[4*q+2] + w.w*s_h2[4*q+3];
  }
  if (tid >= el) e = -1e9f;
  float m = e;
  for (int off = 32; off > 0; off >>= 1) m = fmaxf(m, __shfl_xor(m, off));
  if ((tid & 63) == 0) s_red[tid >> 6] = m;
  __syncthreads();
  if (tid == 0){
    float mm = s_red[0];
    for (int w = 1; w < 8; w++) mm = fmaxf(mm, s_red[w]);
    s_scal[0] = mm;
  }
  __syncthreads();
  float pr = __expf(e - s_scal[0]);
  s_e[tid] = pr;
  float sm = pr;
  for (int off = 32; off > 0; off >>= 1) sm += __shfl_xor(sm, off);
  if ((tid & 63) == 0) s_red[tid >> 6] = sm;
  __syncthreads();
  if (tid == 0){
    float ss = 0.0f;
    for (int w = 0; w < 8; w++) ss += s_red[w];
    s_scal[1] = ss;
  }
  __syncthreads();
  int v = tid & 127, ch = tid >> 7;
  const float* vb = values + ((size_t)n * TE + ch * 128) * KD + v;
  float a = 0.0f;
  #pragma unroll 4
  for (int q = 0; q < 128; q++) a += s_e[ch * 128 + q] * vb[(size_t)q * KD];
  s_part[ch][v] = a;
  __syncthreads();
  if (tid < 128){
    float cv = (s_part[0][tid] + s_part[1][tid] + s_part[2][tid] + s_part[3][tid]) / s_scal[1];
    ctxg[n * KD + tid] = cv;
    aall[((size_t)(t - 1) * NB + n) * 256 + 128 + tid] = f2bf(cv);
  }
}

// ---- output GEMM: out[n][t][v] = aall[t*32+n][:256] . W_out[v][:256] + b_out[v]
// grid (100 vt, 32 rt), block 256; tile 128 r x 80 v, K chunks of 128.
__global__ __launch_bounds__(256) void k_out(
    const u16* __restrict__ aall, const float* __restrict__ wout,
    const float* __restrict__ bout, float* __restrict__ out)
{
  __shared__ __align__(16) u16 sA[128 * 136];
  __shared__ __align__(16) u16 sW[80 * 136];
  int tid = threadIdx.x;
  int vt = blockIdx.x, rt = blockIdx.y;
  int v0 = vt * 80, r0 = rt * 128;
  int rg = tid >> 4, vg = tid & 15;
  float acc[8][5];
  #pragma unroll
  for (int i = 0; i < 8; i++)
    #pragma unroll
    for (int j = 0; j < 5; j++) acc[i][j] = 0.0f;
  for (int kc = 0; kc < 2; kc++){
    int k0 = kc * 128;
    __syncthreads();
    for (int i = tid; i < 128 * 128; i += 256){
      int r = i >> 7, c = i & 127;
      sA[r * 136 + c] = aall[((size_t)(r0 + r)) * 256 + k0 + c];
    }
    for (int i = tid; i < 80 * 128; i += 256){
      int r = i >> 7, c = i & 127;
      sW[r * 136 + c] = f2bf(wout[((size_t)(v0 + r)) * 256 + k0 + c]);
    }
    __syncthreads();
    const u16* ap = sA + (rg * 8) * 136;
    const u16* wp = sW + (vg * 5) * 136;
    for (int kp = 0; kp < 64; kp++){
      u32 av[8], wv[5];
      #pragma unroll
      for (int i = 0; i < 8; i++) av[i] = *(const u32*)(ap + i * 136 + 2 * kp);
      #pragma unroll
      for (int j = 0; j < 5; j++) wv[j] = *(const u32*)(wp + j * 136 + 2 * kp);
      float wlo[5], whi[5];
      #pragma unroll
      for (int j = 0; j < 5; j++){ wlo[j] = bfl(wv[j]); whi[j] = bfh(wv[j]); }
      #pragma unroll
      for (int i = 0; i < 8; i++){
        float a0 = bfl(av[i]), a1 = bfh(av[i]);
        #pragma unroll
        for (int j = 0; j < 5; j++) acc[i][j] += a0 * wlo[j] + a1 * whi[j];
      }
    }
  }
  #pragma unroll
  for (int i = 0; i < 8; i++){
    int r = r0 + rg * 8 + i;
    int tt = r >> 5, nn = r & 31;
    size_t ob = ((size_t)nn * LD + tt) * 8000 + v0 + vg * 5;
    #pragma unroll
    for (int j = 0; j < 5; j++){
      out[ob + j] = acc[i][j] + bout[v0 + vg * 5 + j];
    }
  }
}

extern "C" void kernel_launch(void* const* d_in, const int* in_sizes, int n_in,
                              void* d_out, int out_size, void* d_ws, size_t ws_size,
                              hipStream_t stream)
{
  const float* key    = (const float*)d_in[0];
  const float* values = (const float*)d_in[1];
  const int*   elen   = (const int*)d_in[2];
  const int*   text   = (const int*)d_in[3];
  const float* emb    = (const float*)d_in[4];
  const float* Wih1   = (const float*)d_in[5];
  const float* Whh1   = (const float*)d_in[6];
  const float* bih1   = (const float*)d_in[7];
  const float* bhh1   = (const float*)d_in[8];
  const float* Wih2   = (const float*)d_in[9];
  const float* Whh2   = (const float*)d_in[10];
  const float* bih2   = (const float*)d_in[11];
  const float* bhh2   = (const float*)d_in[12];
  const float* Wout   = (const float*)d_in[13];
  const float* bout   = (const float*)d_in[14];
  float* out = (float*)d_out;
  float* ws = (float*)d_ws;

  float* zb   = ws;                         // zero region base
  float* h1g  = zb;                         // 32768
  float* c1a  = h1g + 32768;                // 32768
  float* c1b  = c1a + 32768;                // 32768
  float* h2g  = c1b + 32768;                // 4096
  float* c2g  = h2g + 4096;                 // 4096   (zero region = 106496 floats)
  float* ctxg = c2g + 4096;                 // 4096
  float* gp1  = ctxg + 4096;                // 2*32*4096 = 262144
  float* gp2  = gp1 + 262144;               // 4*32*512 = 65536
  u16*  aall  = (u16*)(gp2 + 65536);        // 4096*256 u16

  k_init<<<432, 256, 0, stream>>>(zb, values);

  for (int t = 0; t < 128; t++){
    if (t > 0)
      k_attn<<<32, 512, 0, stream>>>(t, key, values, elen, bih2, bhh2,
                                     gp2, h2g, c2g, ctxg, aall);
    k_gates1<<<dim3(256, 2), 256, 0, stream>>>(t, text, emb, Wih1, Whh1, ctxg, h1g, gp1);
    const float* c1in = (t & 1) ? c1b : c1a;
    float* c1out = (t & 1) ? c1a : c1b;
    k_cell1_gates2<<<dim3(4, 16), 256, 0, stream>>>(gp1, bih1, bhh1, c1in, c1out,
                                                    h1g, h2g, Wih2, Whh2, gp2);
  }
  k_attn<<<32, 512, 0, stream>>>(128, key, values, elen, bih2, bhh2,
                                 gp2, h2g, c2g, ctxg, aall);
  k_out<<<dim3(100, 32), 256, 0, stream>>>(aall, Wout, bout, out);
}